// Round 3
// baseline (230.824 us; speedup 1.0000x reference)
//
#include <hip/hip_runtime.h>
#include <cstdint>
#include <cstddef>

// ---------------------------------------------------------------------------
// NeighborTransferModel fused pipeline for MI355X (gfx950) — round 3
//
// Weight folding (rounds 1-2): f@W1 decomposes into neighbor-side GEMM
// (np,nd folded weights) + query-side GEMM + 4 scalar-feature columns.
//
// Round-3 changes:
//  * gemm1: BM=128 x BN=256 x BK=32, 48 KB LDS, 512 thr -> 2 blocks/CU
//    (grid 256x2; bc=1 shares the XCD/L2 with bc=0 for A reuse).
//    Row-pair LDS swizzle (2-way = free) for BK=32 tiles.
//  * cosine-sim fused into gemm1's A staging (simk kernel removed).
//  * gemm2: BM=64 x BK=32, 40 KB LDS, 256 thr, grid 512 -> 4 blocks/CU.
// ---------------------------------------------------------------------------

typedef __attribute__((ext_vector_type(8))) short s16x8;
typedef __attribute__((ext_vector_type(4))) float f32x4;

static __device__ __forceinline__ unsigned short f2bf(float f) {
  unsigned u = __float_as_uint(f);
  u += 0x7fffu + ((u >> 16) & 1u);   // round-to-nearest-even
  return (unsigned short)(u >> 16);
}
static __device__ __forceinline__ float bf2f(unsigned short h) {
  return __uint_as_float(((unsigned)h) << 16);
}

static __device__ __forceinline__ void glds16(const void* g, void* l) {
  __builtin_amdgcn_global_load_lds(
      (const __attribute__((address_space(1))) void*)g,
      (__attribute__((address_space(3))) void*)l, 16, 0, 0);
}

// ---------------------------------------------------------------------------
// Weight-fold kernel (unchanged).
// ---------------------------------------------------------------------------
__global__ void prepw_k(const float* __restrict__ w1, const float* __restrict__ d1,
                        const float* __restrict__ be1, const float* __restrict__ w2,
                        const float* __restrict__ d2,
                        unsigned short* __restrict__ Bt1,
                        unsigned short* __restrict__ Btq,
                        unsigned short* __restrict__ Bt2) {
  const int NB1 = 512 * 1536, NBQ = 768 * 1536, NB2 = 256 * 512;
  for (int idx = blockIdx.x * 256 + threadIdx.x; idx < NB1 + NBQ + NB2;
       idx += gridDim.x * 256) {
    if (idx < NB1) {
      int c = idx / 1536, j = idx - c * 1536;
      const float* W = (c < 256) ? w1 : d1;
      int cc = c & 255;
      float v;
      if (j < 1024) v = W[(1024 + j) * 256 + cc] - W[(2048 + j) * 256 + cc];
      else { int jd = j - 1024; v = W[(3584 + jd) * 256 + cc] - W[(4096 + jd) * 256 + cc]; }
      Bt1[idx] = f2bf(v);
    } else if (idx < NB1 + NBQ) {
      int i2 = idx - NB1;
      int c = i2 / 1536, j = i2 - c * 1536;
      float v;
      if (c < 512) {
        const float* W = (c < 256) ? w1 : d1;
        int cc = c & 255;
        if (j < 1024) v = W[j * 256 + cc] + W[(2048 + j) * 256 + cc];
        else { int jd = j - 1024; v = W[(3072 + jd) * 256 + cc] + W[(4096 + jd) * 256 + cc]; }
      } else {
        v = be1[j * 256 + (c - 512)];
      }
      Btq[i2] = f2bf(v);
    } else {
      int i2 = idx - NB1 - NBQ;
      int c = i2 / 512, j = i2 - c * 512;
      float v = 0.f;
      if (c < 128 && j < 256) v = w2[j * 128 + c];
      else if (c >= 128 && j >= 256) v = d2[(j - 256) * 128 + (c - 128)];
      Bt2[i2] = f2bf(v);
    }
  }
}

// ---------------------------------------------------------------------------
// Query prep (unchanged): Aq bf16 [1024][1536] = [qp | qd], qn = ||qd||
// ---------------------------------------------------------------------------
__global__ void qprep_k(const float* __restrict__ qp, const float* __restrict__ qd,
                        unsigned short* __restrict__ Aq, float* __restrict__ qn) {
  int n = blockIdx.x, t = threadIdx.x;
  const float4* qp4 = (const float4*)(qp + (size_t)n * 1024);
  float4 v = qp4[t];
  ushort4 o4;
  o4.x = f2bf(v.x); o4.y = f2bf(v.y); o4.z = f2bf(v.z); o4.w = f2bf(v.w);
  *(ushort4*)(Aq + (size_t)n * 1536 + t * 4) = o4;
  const float2* qd2 = (const float2*)(qd + (size_t)n * 512);
  float2 w = qd2[t];
  ushort2 o2; o2.x = f2bf(w.x); o2.y = f2bf(w.y);
  *(ushort2*)(Aq + (size_t)n * 1536 + 1024 + t * 2) = o2;
  float ss = w.x * w.x + w.y * w.y;
  #pragma unroll
  for (int m = 32; m >= 1; m >>= 1) ss += __shfl_xor(ss, m);
  __shared__ float sr[4];
  if ((t & 63) == 0) sr[t >> 6] = ss;
  __syncthreads();
  if (t == 0) qn[n] = sqrtf(sr[0] + sr[1] + sr[2] + sr[3]);
}

// ---------------------------------------------------------------------------
// GEMM-0: query GEMM (unchanged round-2 structure). M=1024, Kd=1536, NC=768.
// ---------------------------------------------------------------------------
__global__ __launch_bounds__(256) void gemm0_k(
    const unsigned short* __restrict__ abf, const unsigned short* __restrict__ Bt,
    const float* __restrict__ wb1, const float* __restrict__ db1,
    const float* __restrict__ beb1, float* __restrict__ uq_out) {
  __shared__ short As[128 * 64];
  __shared__ short Bs[128 * 64];
  const int tid = threadIdx.x;
  const int l = tid & 63, w = tid >> 6;
  const int wr = w >> 1, wc = w & 1;
  const int br = blockIdx.x, bc = blockIdx.y;
  const int c0 = bc * 128;
  f32x4 acc[4][4] = {};

  for (int kt = 0; kt < 24; ++kt) {
    const int k0 = kt * 64;
    __syncthreads();
    #pragma unroll
    for (int rep = 0; rep < 4; ++rep) {
      int q = rep * 256 + tid;
      int row = q >> 3, slot = q & 7;
      int kc = slot ^ (row & 7);
      int gk = k0 + kc * 8;
      long grow = (long)br * 128 + row;
      s16x8 pk = *(const s16x8*)(abf + grow * 1536 + gk);
      *(s16x8*)(&As[q * 8]) = pk;
      s16x8 pb = *(const s16x8*)(Bt + (long)(c0 + row) * 1536 + gk);
      *(s16x8*)(&Bs[q * 8]) = pb;
    }
    __syncthreads();
    #pragma unroll
    for (int kh = 0; kh < 2; ++kh) {
      s16x8 af[4], bfr[4];
      #pragma unroll
      for (int mi = 0; mi < 4; ++mi) {
        int ra = wr * 64 + mi * 16 + (l & 15);
        int sidx = (kh * 4 + (l >> 4)) ^ (ra & 7);
        af[mi] = *(const s16x8*)(&As[ra * 64 + sidx * 8]);
      }
      #pragma unroll
      for (int ni = 0; ni < 4; ++ni) {
        int rb = wc * 64 + ni * 16 + (l & 15);
        int sidx = (kh * 4 + (l >> 4)) ^ (rb & 7);
        bfr[ni] = *(const s16x8*)(&Bs[rb * 64 + sidx * 8]);
      }
      #pragma unroll
      for (int mi = 0; mi < 4; ++mi)
        #pragma unroll
        for (int ni = 0; ni < 4; ++ni)
          acc[mi][ni] = __builtin_amdgcn_mfma_f32_16x16x32_bf16(
              af[mi], bfr[ni], acc[mi][ni], 0, 0, 0);
    }
  }
  #pragma unroll
  for (int mi = 0; mi < 4; ++mi)
    #pragma unroll
    for (int ni = 0; ni < 4; ++ni)
      #pragma unroll
      for (int r = 0; r < 4; ++r) {
        int rowl = wr * 64 + mi * 16 + (l >> 4) * 4 + r;
        int coll = wc * 64 + ni * 16 + (l & 15);
        long grow = (long)br * 128 + rowl;
        int gcol = c0 + coll;
        float b = (gcol < 256) ? wb1[gcol]
                 : (gcol < 512) ? db1[gcol - 256] : beb1[gcol - 512];
        uq_out[grow * 768 + gcol] = acc[mi][ni][r] + b;
      }
}

// ---------------------------------------------------------------------------
// GEMM-1: neighbor GEMM.  BM=128, BN=256, BK=32, dbuf 48KB LDS, 512 thr
// (8 waves = 2M x 4N, each 64x64).  2 blocks/CU.  Cosine-sim fused into the
// A staging (fp32 values pass through registers before bf16 cast).
// LDS layout: row-pair swizzle — pair rp=row>>1 owns 128B of 8 16B-slots,
//   slot = (((row&1)<<2)|chunk) ^ (rp&7)   (2-way bank alias = free)
// ---------------------------------------------------------------------------
__global__ __launch_bounds__(512) void gemm1_k(
    const float* __restrict__ Anp, const float* __restrict__ And,
    const unsigned short* __restrict__ Bt,
    const float* __restrict__ uq, const float* __restrict__ aff,
    const float* __restrict__ ppr, const float* __restrict__ trs,
    const float* __restrict__ qd, const float* __restrict__ qn,
    const float* __restrict__ w1, const float* __restrict__ d1,
    unsigned short* __restrict__ h1) {
  __shared__ short As[2][128 * 32];   // 8 KB x2
  __shared__ short Bs[2][256 * 32];   // 16 KB x2
  __shared__ float simLds[128];
  const int tid = threadIdx.x;
  const int l = tid & 63, w = tid >> 6;
  const int wr = w >> 2, wc = w & 3;
  const long br = blockIdx.x;
  const int c0 = blockIdx.y * 256;
  const int arow = tid >> 2, aseg = tid & 3;
  const long agrow = br * 128 + arow;
  const long an = agrow >> 5;

  f32x4 acc[4][4] = {};
  float areg[8], qreg[8];
  float dotp = 0.f, nsp = 0.f;

  auto stageB = [&](int buf, int kt) {
    const int k0 = kt * 32;
    #pragma unroll
    for (int i = 0; i < 2; ++i) {
      int q = i * 512 + tid;             // [0,1024) 16B chunks
      int rp = q >> 3, s = q & 7;
      int sl = s ^ (rp & 7);
      int row = rp * 2 + (sl >> 2), c = sl & 3;
      const unsigned short* src = Bt + (size_t)(c0 + row) * 1536 + k0 + c * 8;
      glds16(src, &Bs[buf][q * 8]);
    }
  };
  auto loadA = [&](int kt) {
    const int k = kt * 32 + aseg * 8;
    const float* src = (k < 1024) ? (Anp + agrow * 1024 + k)
                                  : (And + agrow * 512 + (k - 1024));
    float4 v0 = ((const float4*)src)[0];
    float4 v1 = ((const float4*)src)[1];
    areg[0] = v0.x; areg[1] = v0.y; areg[2] = v0.z; areg[3] = v0.w;
    areg[4] = v1.x; areg[5] = v1.y; areg[6] = v1.z; areg[7] = v1.w;
    if (kt >= 32) {                      // nd region: prefetch qd for sim
      const float* qs = qd + an * 512 + (k - 1024);
      float4 u0 = ((const float4*)qs)[0];
      float4 u1 = ((const float4*)qs)[1];
      qreg[0] = u0.x; qreg[1] = u0.y; qreg[2] = u0.z; qreg[3] = u0.w;
      qreg[4] = u1.x; qreg[5] = u1.y; qreg[6] = u1.z; qreg[7] = u1.w;
    }
  };
  auto writeA = [&](int buf, int kt) {
    if (kt >= 32) {
      #pragma unroll
      for (int j = 0; j < 8; ++j) {
        dotp += areg[j] * qreg[j];
        nsp  += areg[j] * areg[j];
      }
    }
    int sl = (((arow & 1) << 2) | aseg) ^ ((arow >> 1) & 7);
    s16x8 pk;
    #pragma unroll
    for (int e = 0; e < 8; ++e) pk[e] = (short)f2bf(areg[e]);
    *(s16x8*)(&As[buf][(arow >> 1) * 64 + sl * 8]) = pk;
  };

  stageB(0, 0); loadA(0); writeA(0, 0);
  __syncthreads();

  for (int kt = 0; kt < 48; ++kt) {
    const int cur = kt & 1, nxt = cur ^ 1;
    if (kt < 47) { stageB(nxt, kt + 1); loadA(kt + 1); }
    s16x8 af[4], bfr[4];
    const int c = l >> 4;
    #pragma unroll
    for (int mi = 0; mi < 4; ++mi) {
      int ra = wr * 64 + mi * 16 + (l & 15);
      int sl = (((ra & 1) << 2) | c) ^ ((ra >> 1) & 7);
      af[mi] = *(const s16x8*)(&As[cur][(ra >> 1) * 64 + sl * 8]);
    }
    #pragma unroll
    for (int ni = 0; ni < 4; ++ni) {
      int rb = wc * 64 + ni * 16 + (l & 15);
      int sl = (((rb & 1) << 2) | c) ^ ((rb >> 1) & 7);
      bfr[ni] = *(const s16x8*)(&Bs[cur][(rb >> 1) * 64 + sl * 8]);
    }
    __builtin_amdgcn_s_setprio(1);
    #pragma unroll
    for (int mi = 0; mi < 4; ++mi)
      #pragma unroll
      for (int ni = 0; ni < 4; ++ni)
        acc[mi][ni] = __builtin_amdgcn_mfma_f32_16x16x32_bf16(
            af[mi], bfr[ni], acc[mi][ni], 0, 0, 0);
    __builtin_amdgcn_s_setprio(0);
    if (kt < 47) writeA(nxt, kt + 1);
    __syncthreads();
  }

  // ---- cosine-sim: reduce over the 4 k-segments (lanes l^1, l^2) ----
  float dv = dotp, nv = nsp;
  dv += __shfl_xor(dv, 1); dv += __shfl_xor(dv, 2);
  nv += __shfl_xor(nv, 1); nv += __shfl_xor(nv, 2);
  if (aseg == 0) {
    float qv = qn[an];
    simLds[arow] = dv / (fmaxf(qv, 1e-8f) * fmaxf(sqrtf(nv), 1e-8f));
  }
  __syncthreads();

  // ---- epilogue ----
  #pragma unroll
  for (int mi = 0; mi < 4; ++mi) {
    #pragma unroll
    for (int r = 0; r < 4; ++r) {
      int rowl = wr * 64 + mi * 16 + (l >> 4) * 4 + r;
      long grow = br * 128 + rowl;
      float sa = aff[grow], sp = ppr[grow], st = trs[grow];
      float ss = simLds[rowl];
      long n = grow >> 5;
      #pragma unroll
      for (int ni = 0; ni < 4; ++ni) {
        int gcol = c0 + wc * 64 + ni * 16 + (l & 15);
        const float* W = (gcol < 256) ? w1 : d1;
        int cc = gcol & 255;
        float sv = sa * W[4608 * 256 + cc] + sp * W[4609 * 256 + cc]
                 + st * W[4610 * 256 + cc] + ss * W[4611 * 256 + cc];
        float x = acc[mi][ni][r] + uq[n * 768 + gcol] + sv;
        h1[grow * 512 + gcol] = f2bf(fmaxf(x, 0.f));
      }
    }
  }
}

// ---------------------------------------------------------------------------
// GEMM-2 + fused layer-3.  BM=64, NC=256, BK=32, 256 thr (4 waves, N-split),
// 40KB LDS -> 4 blocks/CU, grid 512.  All staging via global_load_lds with
// the row-pair swizzle.  Epilogue: h2=relu(acc+b2); logits/delta dots.
// ---------------------------------------------------------------------------
__global__ __launch_bounds__(256) void gemm2_k(
    const unsigned short* __restrict__ h1, const unsigned short* __restrict__ Bt2,
    const float* __restrict__ wb2, const float* __restrict__ db2,
    const float* __restrict__ w3, const float* __restrict__ wb3,
    const float* __restrict__ d3, const float* __restrict__ db3,
    float* __restrict__ ld) {
  __shared__ short As[2][64 * 32];    // 4 KB x2
  __shared__ short Bs[2][256 * 32];   // 16 KB x2
  __shared__ float part[4][64];
  const int tid = threadIdx.x;
  const int l = tid & 63, wc = tid >> 6;
  const long br = blockIdx.x;

  f32x4 acc[4][4] = {};

  auto stageA = [&](int buf, int kt) {
    int q = tid;                         // [0,256)
    int rp = q >> 3, s = q & 7;
    int sl = s ^ (rp & 7);
    int row = rp * 2 + (sl >> 2), c = sl & 3;
    const unsigned short* src = h1 + (br * 64 + row) * 512 + kt * 32 + c * 8;
    glds16(src, &As[buf][q * 8]);
  };
  auto stageB = [&](int buf, int kt) {
    #pragma unroll
    for (int i = 0; i < 4; ++i) {
      int q = i * 256 + tid;             // [0,1024)
      int rp = q >> 3, s = q & 7;
      int sl = s ^ (rp & 7);
      int row = rp * 2 + (sl >> 2), c = sl & 3;
      const unsigned short* src = Bt2 + (size_t)row * 512 + kt * 32 + c * 8;
      glds16(src, &Bs[buf][q * 8]);
    }
  };

  stageA(0, 0); stageB(0, 0);
  __syncthreads();

  for (int kt = 0; kt < 16; ++kt) {
    const int cur = kt & 1, nxt = cur ^ 1;
    if (kt < 15) { stageA(nxt, kt + 1); stageB(nxt, kt + 1); }
    s16x8 af[4], bfr[4];
    const int c = l >> 4;
    #pragma unroll
    for (int mi = 0; mi < 4; ++mi) {
      int ra = mi * 16 + (l & 15);
      int sl = (((ra & 1) << 2) | c) ^ ((ra >> 1) & 7);
      af[mi] = *(const s16x8*)(&As[cur][(ra >> 1) * 64 + sl * 8]);
    }
    #pragma unroll
    for (int ni = 0; ni < 4; ++ni) {
      int rb = wc * 64 + ni * 16 + (l & 15);
      int sl = (((rb & 1) << 2) | c) ^ ((rb >> 1) & 7);
      bfr[ni] = *(const s16x8*)(&Bs[cur][(rb >> 1) * 64 + sl * 8]);
    }
    __builtin_amdgcn_s_setprio(1);
    #pragma unroll
    for (int mi = 0; mi < 4; ++mi)
      #pragma unroll
      for (int ni = 0; ni < 4; ++ni)
        acc[mi][ni] = __builtin_amdgcn_mfma_f32_16x16x32_bf16(
            af[mi], bfr[ni], acc[mi][ni], 0, 0, 0);
    __builtin_amdgcn_s_setprio(0);
    __syncthreads();
  }

  // ---- fused layer-2 bias/relu + layer-3 dot ----
  float coef[4], b2[4];
  #pragma unroll
  for (int ni = 0; ni < 4; ++ni) {
    int col = wc * 64 + ni * 16 + (l & 15);
    coef[ni] = (col < 128) ? w3[col] : d3[col - 128];
    b2[ni]   = (col < 128) ? wb2[col] : db2[col - 128];
  }
  #pragma unroll
  for (int mi = 0; mi < 4; ++mi) {
    #pragma unroll
    for (int rr = 0; rr < 4; ++rr) {
      float p = 0.f;
      #pragma unroll
      for (int ni = 0; ni < 4; ++ni) {
        float x = fmaxf(acc[mi][ni][rr] + b2[ni], 0.f);
        p += x * coef[ni];
      }
      #pragma unroll
      for (int m = 1; m <= 8; m <<= 1) p += __shfl_xor(p, m);
      if ((l & 15) == 0)
        part[wc][mi * 16 + (l >> 4) * 4 + rr] = p;
    }
  }
  __syncthreads();
  if (tid < 128) {
    int row = tid >> 1, hf = tid & 1;
    long grow = br * 64 + row;
    float v = hf ? (part[2][row] + part[3][row] + db3[0])
                 : (part[0][row] + part[1][row] + wb3[0]);
    ld[(size_t)hf * 32768 + grow] = v;
  }
}

// ---------------------------------------------------------------------------
// Finalize: masked softmax over K=32, prior, mu/sigma. (unchanged)
// ---------------------------------------------------------------------------
__global__ void finalize2_k(const float* __restrict__ uq, const float* __restrict__ ld,
                            const float* __restrict__ be2, const float* __restrict__ beb2,
                            const int* __restrict__ mask, const float* __restrict__ aff,
                            const float* __restrict__ lsg, float* __restrict__ out) {
  int n = blockIdx.x, t = threadIdx.x;
  __shared__ float s_red[4];
  float x = uq[(size_t)n * 768 + 512 + t];
  float pp = fmaxf(x, 0.f) * be2[t];
  #pragma unroll
  for (int m = 32; m >= 1; m >>= 1) pp += __shfl_xor(pp, m);
  if ((t & 63) == 0) s_red[t >> 6] = pp;
  __syncthreads();
  if (t < 64) {
    int kk = t & 31;
    int m = mask[n * 32 + kk];
    float lg = m ? ld[n * 32 + kk] : -1e9f;
    float dl = ld[32768 + n * 32 + kk];
    float mx = lg;
    #pragma unroll
    for (int mm = 16; mm >= 1; mm >>= 1) mx = fmaxf(mx, __shfl_xor(mx, mm));
    float e = expf(lg - mx);
    float s = e;
    #pragma unroll
    for (int mm = 16; mm >= 1; mm >>= 1) s += __shfl_xor(s, mm);
    float wgt = (e / s) * (m ? 1.f : 0.f);
    float nrm = wgt;
    #pragma unroll
    for (int mm = 16; mm >= 1; mm >>= 1) nrm += __shfl_xor(nrm, mm);
    wgt = (nrm > 0.f) ? wgt / fmaxf(nrm, 1e-8f) : 0.f;
    float tr = wgt * aff[n * 32 + kk];
    float co = wgt * dl;
    int am = m;
    #pragma unroll
    for (int mm = 16; mm >= 1; mm >>= 1) {
      tr += __shfl_xor(tr, mm);
      co += __shfl_xor(co, mm);
      am |= __shfl_xor(am, mm);
    }
    if (t == 0) {
      float prior = s_red[0] + s_red[1] + s_red[2] + s_red[3] + beb2[0] + 6.5f;
      float l0 = lsg[0];
      float sp = (l0 > 20.f) ? l0 : log1pf(expf(l0));
      float mu = am ? (tr + co) : prior;
      float sg = sp + (am ? 0.f : 0.15f) + 1e-4f;
      out[n] = mu;
      out[1024 + n] = sg;
    }
  }
}

// ---------------------------------------------------------------------------
extern "C" void kernel_launch(void* const* d_in, const int* in_sizes, int n_in,
                              void* d_out, int out_size, void* d_ws, size_t ws_size,
                              hipStream_t stream) {
  const float* np_ = (const float*)d_in[0];
  const float* nd_ = (const float*)d_in[1];
  const float* aff = (const float*)d_in[2];
  const float* ppr = (const float*)d_in[3];
  const float* trs = (const float*)d_in[4];
  const int*   msk = (const int*)d_in[5];
  const float* qp  = (const float*)d_in[6];
  const float* qd  = (const float*)d_in[7];
  const float* w1  = (const float*)d_in[8];
  const float* wb1 = (const float*)d_in[9];
  const float* w2  = (const float*)d_in[10];
  const float* wb2 = (const float*)d_in[11];
  const float* w3  = (const float*)d_in[12];
  const float* wb3 = (const float*)d_in[13];
  const float* d1  = (const float*)d_in[14];
  const float* db1 = (const float*)d_in[15];
  const float* d2  = (const float*)d_in[16];
  const float* db2 = (const float*)d_in[17];
  const float* d3  = (const float*)d_in[18];
  const float* db3 = (const float*)d_in[19];
  const float* be1 = (const float*)d_in[20];
  const float* beb1 = (const float*)d_in[21];
  const float* be2 = (const float*)d_in[22];
  const float* beb2 = (const float*)d_in[23];
  const float* lsg = (const float*)d_in[24];
  float* out = (float*)d_out;

  char* ws = (char*)d_ws;
  size_t off = 0;
  auto carve = [&](size_t bytes) -> void* {
    void* p = ws + off;
    off += (bytes + 511) & ~(size_t)511;
    return p;
  };
  float*          uq  = (float*)carve(1024ull * 768 * 4);
  unsigned short* h1  = (unsigned short*)carve(32768ull * 512 * 2);
  float*          ld  = (float*)carve(2ull * 32768 * 4);
  unsigned short* Bt1 = (unsigned short*)carve(512ull * 1536 * 2);
  unsigned short* Btq = (unsigned short*)carve(768ull * 1536 * 2);
  unsigned short* Bt2 = (unsigned short*)carve(256ull * 512 * 2);
  unsigned short* Aq  = (unsigned short*)carve(1024ull * 1536 * 2);
  float*          qn  = (float*)carve(1024ull * 4);
  (void)ws_size; (void)in_sizes; (void)n_in; (void)out_size;

  prepw_k<<<2048, 256, 0, stream>>>(w1, d1, be1, w2, d2, Bt1, Btq, Bt2);
  qprep_k<<<1024, 256, 0, stream>>>(qp, qd, Aq, qn);

  gemm0_k<<<dim3(8, 6), 256, 0, stream>>>(Aq, Btq, wb1, db1, beb1, uq);

  gemm1_k<<<dim3(256, 2), 512, 0, stream>>>(np_, nd_, Bt1, uq, aff, ppr, trs,
                                            qd, qn, w1, d1, h1);

  gemm2_k<<<512, 256, 0, stream>>>(h1, Bt2, wb2, db2, w3, wb3, d3, db3, ld);

  finalize2_k<<<1024, 256, 0, stream>>>(uq, ld, be2, beb2, msk, aff, lsg, out);
}

// Round 4
// 155.374 us; speedup vs baseline: 1.4856x; 1.4856x over previous
//
#include <hip/hip_runtime.h>
#include <cstdint>
#include <cstddef>

// ---------------------------------------------------------------------------
// NeighborTransferModel fused pipeline for MI355X (gfx950) — round 4
//
// Weight folding (rounds 1-3): f@W1 decomposes into neighbor-side GEMM
// (np,nd folded weights) + query-side GEMM + 4 scalar-feature columns.
//
// Round-4 changes (gemm1 only; gemm2 kept from r3, rest from r2):
//  * gemm1 back to BM=128 x BN=512 x BK=64, 160KB dbuf LDS, 8 waves —
//    the round-2 geometry (115 us) — with the m201-style phase schedule:
//    4 phases per K-step, ONE raw s_barrier per step, counted vmcnt(4)
//    at step entry (B stage-loads stay in flight across the barrier),
//    lgkmcnt(0)+sched_barrier(0) before each MFMA cluster, setprio(1)
//    around MFMA.  Cosine-sim fused into A staging (simLds aliases As).
// ---------------------------------------------------------------------------

typedef __attribute__((ext_vector_type(8))) short s16x8;
typedef __attribute__((ext_vector_type(4))) float f32x4;

static __device__ __forceinline__ unsigned short f2bf(float f) {
  unsigned u = __float_as_uint(f);
  u += 0x7fffu + ((u >> 16) & 1u);   // round-to-nearest-even
  return (unsigned short)(u >> 16);
}
static __device__ __forceinline__ float bf2f(unsigned short h) {
  return __uint_as_float(((unsigned)h) << 16);
}

static __device__ __forceinline__ void glds16(const void* g, void* l) {
  __builtin_amdgcn_global_load_lds(
      (const __attribute__((address_space(1))) void*)g,
      (__attribute__((address_space(3))) void*)l, 16, 0, 0);
}

// ---------------------------------------------------------------------------
// Weight-fold kernel (unchanged).
// ---------------------------------------------------------------------------
__global__ void prepw_k(const float* __restrict__ w1, const float* __restrict__ d1,
                        const float* __restrict__ be1, const float* __restrict__ w2,
                        const float* __restrict__ d2,
                        unsigned short* __restrict__ Bt1,
                        unsigned short* __restrict__ Btq,
                        unsigned short* __restrict__ Bt2) {
  const int NB1 = 512 * 1536, NBQ = 768 * 1536, NB2 = 256 * 512;
  for (int idx = blockIdx.x * 256 + threadIdx.x; idx < NB1 + NBQ + NB2;
       idx += gridDim.x * 256) {
    if (idx < NB1) {
      int c = idx / 1536, j = idx - c * 1536;
      const float* W = (c < 256) ? w1 : d1;
      int cc = c & 255;
      float v;
      if (j < 1024) v = W[(1024 + j) * 256 + cc] - W[(2048 + j) * 256 + cc];
      else { int jd = j - 1024; v = W[(3584 + jd) * 256 + cc] - W[(4096 + jd) * 256 + cc]; }
      Bt1[idx] = f2bf(v);
    } else if (idx < NB1 + NBQ) {
      int i2 = idx - NB1;
      int c = i2 / 1536, j = i2 - c * 1536;
      float v;
      if (c < 512) {
        const float* W = (c < 256) ? w1 : d1;
        int cc = c & 255;
        if (j < 1024) v = W[j * 256 + cc] + W[(2048 + j) * 256 + cc];
        else { int jd = j - 1024; v = W[(3072 + jd) * 256 + cc] + W[(4096 + jd) * 256 + cc]; }
      } else {
        v = be1[j * 256 + (c - 512)];
      }
      Btq[i2] = f2bf(v);
    } else {
      int i2 = idx - NB1 - NBQ;
      int c = i2 / 512, j = i2 - c * 512;
      float v = 0.f;
      if (c < 128 && j < 256) v = w2[j * 128 + c];
      else if (c >= 128 && j >= 256) v = d2[(j - 256) * 128 + (c - 128)];
      Bt2[i2] = f2bf(v);
    }
  }
}

// ---------------------------------------------------------------------------
// Query prep (unchanged): Aq bf16 [1024][1536] = [qp | qd], qn = ||qd||
// ---------------------------------------------------------------------------
__global__ void qprep_k(const float* __restrict__ qp, const float* __restrict__ qd,
                        unsigned short* __restrict__ Aq, float* __restrict__ qn) {
  int n = blockIdx.x, t = threadIdx.x;
  const float4* qp4 = (const float4*)(qp + (size_t)n * 1024);
  float4 v = qp4[t];
  ushort4 o4;
  o4.x = f2bf(v.x); o4.y = f2bf(v.y); o4.z = f2bf(v.z); o4.w = f2bf(v.w);
  *(ushort4*)(Aq + (size_t)n * 1536 + t * 4) = o4;
  const float2* qd2 = (const float2*)(qd + (size_t)n * 512);
  float2 w = qd2[t];
  ushort2 o2; o2.x = f2bf(w.x); o2.y = f2bf(w.y);
  *(ushort2*)(Aq + (size_t)n * 1536 + 1024 + t * 2) = o2;
  float ss = w.x * w.x + w.y * w.y;
  #pragma unroll
  for (int m = 32; m >= 1; m >>= 1) ss += __shfl_xor(ss, m);
  __shared__ float sr[4];
  if ((t & 63) == 0) sr[t >> 6] = ss;
  __syncthreads();
  if (t == 0) qn[n] = sqrtf(sr[0] + sr[1] + sr[2] + sr[3]);
}

// ---------------------------------------------------------------------------
// GEMM-0: query GEMM (unchanged). M=1024, Kd=1536, NC=768.
// ---------------------------------------------------------------------------
__global__ __launch_bounds__(256) void gemm0_k(
    const unsigned short* __restrict__ abf, const unsigned short* __restrict__ Bt,
    const float* __restrict__ wb1, const float* __restrict__ db1,
    const float* __restrict__ beb1, float* __restrict__ uq_out) {
  __shared__ short As[128 * 64];
  __shared__ short Bs[128 * 64];
  const int tid = threadIdx.x;
  const int l = tid & 63, w = tid >> 6;
  const int wr = w >> 1, wc = w & 1;
  const int br = blockIdx.x, bc = blockIdx.y;
  const int c0 = bc * 128;
  f32x4 acc[4][4] = {};

  for (int kt = 0; kt < 24; ++kt) {
    const int k0 = kt * 64;
    __syncthreads();
    #pragma unroll
    for (int rep = 0; rep < 4; ++rep) {
      int q = rep * 256 + tid;
      int row = q >> 3, slot = q & 7;
      int kc = slot ^ (row & 7);
      int gk = k0 + kc * 8;
      long grow = (long)br * 128 + row;
      s16x8 pk = *(const s16x8*)(abf + grow * 1536 + gk);
      *(s16x8*)(&As[q * 8]) = pk;
      s16x8 pb = *(const s16x8*)(Bt + (long)(c0 + row) * 1536 + gk);
      *(s16x8*)(&Bs[q * 8]) = pb;
    }
    __syncthreads();
    #pragma unroll
    for (int kh = 0; kh < 2; ++kh) {
      s16x8 af[4], bfr[4];
      #pragma unroll
      for (int mi = 0; mi < 4; ++mi) {
        int ra = wr * 64 + mi * 16 + (l & 15);
        int sidx = (kh * 4 + (l >> 4)) ^ (ra & 7);
        af[mi] = *(const s16x8*)(&As[ra * 64 + sidx * 8]);
      }
      #pragma unroll
      for (int ni = 0; ni < 4; ++ni) {
        int rb = wc * 64 + ni * 16 + (l & 15);
        int sidx = (kh * 4 + (l >> 4)) ^ (rb & 7);
        bfr[ni] = *(const s16x8*)(&Bs[rb * 64 + sidx * 8]);
      }
      #pragma unroll
      for (int mi = 0; mi < 4; ++mi)
        #pragma unroll
        for (int ni = 0; ni < 4; ++ni)
          acc[mi][ni] = __builtin_amdgcn_mfma_f32_16x16x32_bf16(
              af[mi], bfr[ni], acc[mi][ni], 0, 0, 0);
    }
  }
  #pragma unroll
  for (int mi = 0; mi < 4; ++mi)
    #pragma unroll
    for (int ni = 0; ni < 4; ++ni)
      #pragma unroll
      for (int r = 0; r < 4; ++r) {
        int rowl = wr * 64 + mi * 16 + (l >> 4) * 4 + r;
        int coll = wc * 64 + ni * 16 + (l & 15);
        long grow = (long)br * 128 + rowl;
        int gcol = c0 + coll;
        float b = (gcol < 256) ? wb1[gcol]
                 : (gcol < 512) ? db1[gcol - 256] : beb1[gcol - 512];
        uq_out[grow * 768 + gcol] = acc[mi][ni][r] + b;
      }
}

// ---------------------------------------------------------------------------
// GEMM-1: neighbor GEMM.  BM=128, BN=512, BK=64, dbuf 160KB LDS, 8 waves
// (2M x 4N, each 64x128).  4-phase K-step, ONE raw s_barrier per step,
// counted vmcnt(4) at entry.  Cosine-sim fused into A staging.
// ---------------------------------------------------------------------------
__global__ __launch_bounds__(512, 2) void gemm1_k(
    const float* __restrict__ Anp, const float* __restrict__ And,
    const unsigned short* __restrict__ Bt,
    const float* __restrict__ uq, const float* __restrict__ aff,
    const float* __restrict__ ppr, const float* __restrict__ trs,
    const float* __restrict__ qd, const float* __restrict__ qn,
    const float* __restrict__ w1, const float* __restrict__ d1,
    unsigned short* __restrict__ h1) {
  __shared__ short As[2][128 * 64];   // 16 KB x2
  __shared__ short Bs[2][512 * 64];   // 64 KB x2  -> exactly 160 KiB
  const int tid = threadIdx.x;
  const int l = tid & 63, w = tid >> 6;
  const int wr = w >> 2, wc = w & 3;
  const long br = blockIdx.x;
  const int arow = tid >> 2, aseg = tid & 3;
  const long agrow = br * 128 + arow;
  const long an = agrow >> 5;
  const int brow = tid >> 3, bslot = tid & 7;

  f32x4 acc[4][8] = {};
  float areg[16], qreg[16];
  float dotp = 0.f, nsp = 0.f;

  auto stageBhalf = [&](int buf, int kt, int h) {
    const int k0 = kt * 64;
    #pragma unroll
    for (int i = 0; i < 4; ++i) {
      int idx = h * 4 + i;
      int row = idx * 64 + brow;
      const unsigned short* src =
          Bt + (size_t)row * 1536 + k0 + ((bslot ^ (row & 7)) * 8);
      glds16(src, &Bs[buf][(idx * 512 + tid) * 8]);
    }
  };
  auto loadA = [&](int kt) {
    const int k0 = kt * 64 + aseg * 16;
    const float* src = (k0 < 1024) ? (Anp + agrow * 1024 + k0)
                                   : (And + agrow * 512 + (k0 - 1024));
    #pragma unroll
    for (int i = 0; i < 4; ++i) {
      float4 v = ((const float4*)src)[i];
      areg[i * 4 + 0] = v.x; areg[i * 4 + 1] = v.y;
      areg[i * 4 + 2] = v.z; areg[i * 4 + 3] = v.w;
    }
    if (kt >= 16) {                      // nd region: qd for fused cosine-sim
      const float* qs = qd + an * 512 + (k0 - 1024);
      #pragma unroll
      for (int i = 0; i < 4; ++i) {
        float4 v = ((const float4*)qs)[i];
        qreg[i * 4 + 0] = v.x; qreg[i * 4 + 1] = v.y;
        qreg[i * 4 + 2] = v.z; qreg[i * 4 + 3] = v.w;
      }
    }
  };
  auto writeA = [&](int buf, int kt) {
    if (kt >= 16) {
      #pragma unroll
      for (int j = 0; j < 16; ++j) {
        dotp += areg[j] * qreg[j];
        nsp  += areg[j] * areg[j];
      }
    }
    #pragma unroll
    for (int j = 0; j < 2; ++j) {
      int slot = (aseg * 2 + j) ^ (arow & 7);
      s16x8 pk;
      #pragma unroll
      for (int e = 0; e < 8; ++e) pk[e] = (short)f2bf(areg[j * 8 + e]);
      *(s16x8*)(&As[buf][arow * 64 + slot * 8]) = pk;
    }
  };

  const int c = l >> 4;
  auto rdA = [&](int cur, int kh, s16x8* af) {
    #pragma unroll
    for (int mi = 0; mi < 4; ++mi) {
      int ra = wr * 64 + mi * 16 + (l & 15);
      int sl = (kh * 4 + c) ^ (ra & 7);
      af[mi] = *(const s16x8*)(&As[cur][ra * 64 + sl * 8]);
    }
  };
  auto rdB = [&](int cur, int kh, int nh, s16x8* bfr) {
    #pragma unroll
    for (int ni = 0; ni < 4; ++ni) {
      int rb = wc * 128 + (nh * 4 + ni) * 16 + (l & 15);
      int sl = (kh * 4 + c) ^ (rb & 7);
      bfr[ni] = *(const s16x8*)(&Bs[cur][rb * 64 + sl * 8]);
    }
  };

  // ---- prologue: stage buffer 0 fully, full drain ----
  loadA(0);
  stageBhalf(0, 0, 0); stageBhalf(0, 0, 1);
  writeA(0, 0);
  __syncthreads();

  for (int kt = 0; kt < 24; ++kt) {
    const int cur = kt & 1, nxt = cur ^ 1;
    // ---- step entry: counted drain of last step's 8 B-glds ----
    if (kt < 23) {
      loadA(kt + 1);                     // 4 vmem, stay in flight to phase 3
      asm volatile("s_waitcnt vmcnt(4)" ::: "memory");
    } else {
      asm volatile("s_waitcnt vmcnt(0)" ::: "memory");
    }
    asm volatile("s_waitcnt lgkmcnt(0)" ::: "memory");
    __builtin_amdgcn_s_barrier();
    __builtin_amdgcn_sched_barrier(0);

    s16x8 af[4], bfr[4];
    // ---- phase 0: kh=0, ni 0..3 ----
    rdA(cur, 0, af); rdB(cur, 0, 0, bfr);
    asm volatile("s_waitcnt lgkmcnt(0)" ::: "memory");
    __builtin_amdgcn_sched_barrier(0);
    __builtin_amdgcn_s_setprio(1);
    #pragma unroll
    for (int mi = 0; mi < 4; ++mi)
      #pragma unroll
      for (int ni = 0; ni < 4; ++ni)
        acc[mi][ni] = __builtin_amdgcn_mfma_f32_16x16x32_bf16(
            af[mi], bfr[ni], acc[mi][ni], 0, 0, 0);
    __builtin_amdgcn_s_setprio(0);
    // ---- phase 1: kh=0, ni 4..7 (+stage B half 0) ----
    if (kt < 23) stageBhalf(nxt, kt + 1, 0);
    rdB(cur, 0, 1, bfr);
    asm volatile("s_waitcnt lgkmcnt(0)" ::: "memory");
    __builtin_amdgcn_sched_barrier(0);
    __builtin_amdgcn_s_setprio(1);
    #pragma unroll
    for (int mi = 0; mi < 4; ++mi)
      #pragma unroll
      for (int ni = 0; ni < 4; ++ni)
        acc[mi][4 + ni] = __builtin_amdgcn_mfma_f32_16x16x32_bf16(
            af[mi], bfr[ni], acc[mi][4 + ni], 0, 0, 0);
    __builtin_amdgcn_s_setprio(0);
    // ---- phase 2: kh=1, ni 0..3 (+stage B half 1) ----
    if (kt < 23) stageBhalf(nxt, kt + 1, 1);
    rdA(cur, 1, af); rdB(cur, 1, 0, bfr);
    asm volatile("s_waitcnt lgkmcnt(0)" ::: "memory");
    __builtin_amdgcn_sched_barrier(0);
    __builtin_amdgcn_s_setprio(1);
    #pragma unroll
    for (int mi = 0; mi < 4; ++mi)
      #pragma unroll
      for (int ni = 0; ni < 4; ++ni)
        acc[mi][ni] = __builtin_amdgcn_mfma_f32_16x16x32_bf16(
            af[mi], bfr[ni], acc[mi][ni], 0, 0, 0);
    __builtin_amdgcn_s_setprio(0);
    // ---- phase 3: kh=1, ni 4..7 (+writeA: compiler-waits A loads, keeps B) ----
    if (kt < 23) writeA(nxt, kt + 1);
    rdB(cur, 1, 1, bfr);
    asm volatile("s_waitcnt lgkmcnt(0)" ::: "memory");
    __builtin_amdgcn_sched_barrier(0);
    __builtin_amdgcn_s_setprio(1);
    #pragma unroll
    for (int mi = 0; mi < 4; ++mi)
      #pragma unroll
      for (int ni = 0; ni < 4; ++ni)
        acc[mi][4 + ni] = __builtin_amdgcn_mfma_f32_16x16x32_bf16(
            af[mi], bfr[ni], acc[mi][4 + ni], 0, 0, 0);
    __builtin_amdgcn_s_setprio(0);
  }

  // ---- cosine-sim: reduce over the 4 k-segments; simLds aliases As ----
  float* simLds = (float*)&As[0][0];
  float dv = dotp, nv = nsp;
  dv += __shfl_xor(dv, 1); dv += __shfl_xor(dv, 2);
  nv += __shfl_xor(nv, 1); nv += __shfl_xor(nv, 2);
  __syncthreads();                       // all LDS reads done before aliasing
  if (aseg == 0) {
    float qv = qn[an];
    simLds[arow] = dv / (fmaxf(qv, 1e-8f) * fmaxf(sqrtf(nv), 1e-8f));
  }
  __syncthreads();

  // ---- epilogue ----
  #pragma unroll
  for (int mi = 0; mi < 4; ++mi) {
    #pragma unroll
    for (int r = 0; r < 4; ++r) {
      int rowl = wr * 64 + mi * 16 + (l >> 4) * 4 + r;
      long grow = br * 128 + rowl;
      float sa = aff[grow], sp = ppr[grow], st = trs[grow];
      float ss = simLds[rowl];
      long n = grow >> 5;
      #pragma unroll
      for (int ni = 0; ni < 8; ++ni) {
        int gcol = wc * 128 + ni * 16 + (l & 15);
        const float* W = (gcol < 256) ? w1 : d1;
        int cc = gcol & 255;
        float sv = sa * W[4608 * 256 + cc] + sp * W[4609 * 256 + cc]
                 + st * W[4610 * 256 + cc] + ss * W[4611 * 256 + cc];
        float x = acc[mi][ni][r] + uq[n * 768 + gcol] + sv;
        h1[grow * 512 + gcol] = f2bf(fmaxf(x, 0.f));
      }
    }
  }
}

// ---------------------------------------------------------------------------
// GEMM-2 + fused layer-3 (round-3 version).  BM=64, NC=256, BK=32, 256 thr,
// 40KB LDS -> 4 blocks/CU, grid 512.
// ---------------------------------------------------------------------------
__global__ __launch_bounds__(256) void gemm2_k(
    const unsigned short* __restrict__ h1, const unsigned short* __restrict__ Bt2,
    const float* __restrict__ wb2, const float* __restrict__ db2,
    const float* __restrict__ w3, const float* __restrict__ wb3,
    const float* __restrict__ d3, const float* __restrict__ db3,
    float* __restrict__ ld) {
  __shared__ short As[2][64 * 32];    // 4 KB x2
  __shared__ short Bs[2][256 * 32];   // 16 KB x2
  __shared__ float part[4][64];
  const int tid = threadIdx.x;
  const int l = tid & 63, wc = tid >> 6;
  const long br = blockIdx.x;

  f32x4 acc[4][4] = {};

  auto stageA = [&](int buf, int kt) {
    int q = tid;                         // [0,256)
    int rp = q >> 3, s = q & 7;
    int sl = s ^ (rp & 7);
    int row = rp * 2 + (sl >> 2), c = sl & 3;
    const unsigned short* src = h1 + (br * 64 + row) * 512 + kt * 32 + c * 8;
    glds16(src, &As[buf][q * 8]);
  };
  auto stageB = [&](int buf, int kt) {
    #pragma unroll
    for (int i = 0; i < 4; ++i) {
      int q = i * 256 + tid;             // [0,1024)
      int rp = q >> 3, s = q & 7;
      int sl = s ^ (rp & 7);
      int row = rp * 2 + (sl >> 2), c = sl & 3;
      const unsigned short* src = Bt2 + (size_t)row * 512 + kt * 32 + c * 8;
      glds16(src, &Bs[buf][q * 8]);
    }
  };

  stageA(0, 0); stageB(0, 0);
  __syncthreads();

  for (int kt = 0; kt < 16; ++kt) {
    const int cur = kt & 1, nxt = cur ^ 1;
    if (kt < 15) { stageA(nxt, kt + 1); stageB(nxt, kt + 1); }
    s16x8 af[4], bfr[4];
    const int c = l >> 4;
    #pragma unroll
    for (int mi = 0; mi < 4; ++mi) {
      int ra = mi * 16 + (l & 15);
      int sl = (((ra & 1) << 2) | c) ^ ((ra >> 1) & 7);
      af[mi] = *(const s16x8*)(&As[cur][(ra >> 1) * 64 + sl * 8]);
    }
    #pragma unroll
    for (int ni = 0; ni < 4; ++ni) {
      int rb = wc * 64 + ni * 16 + (l & 15);
      int sl = (((rb & 1) << 2) | c) ^ ((rb >> 1) & 7);
      bfr[ni] = *(const s16x8*)(&Bs[cur][(rb >> 1) * 64 + sl * 8]);
    }
    __builtin_amdgcn_s_setprio(1);
    #pragma unroll
    for (int mi = 0; mi < 4; ++mi)
      #pragma unroll
      for (int ni = 0; ni < 4; ++ni)
        acc[mi][ni] = __builtin_amdgcn_mfma_f32_16x16x32_bf16(
            af[mi], bfr[ni], acc[mi][ni], 0, 0, 0);
    __builtin_amdgcn_s_setprio(0);
    __syncthreads();
  }

  // ---- fused layer-2 bias/relu + layer-3 dot ----
  float coef[4], b2[4];
  #pragma unroll
  for (int ni = 0; ni < 4; ++ni) {
    int col = wc * 64 + ni * 16 + (l & 15);
    coef[ni] = (col < 128) ? w3[col] : d3[col - 128];
    b2[ni]   = (col < 128) ? wb2[col] : db2[col - 128];
  }
  #pragma unroll
  for (int mi = 0; mi < 4; ++mi) {
    #pragma unroll
    for (int rr = 0; rr < 4; ++rr) {
      float p = 0.f;
      #pragma unroll
      for (int ni = 0; ni < 4; ++ni) {
        float x = fmaxf(acc[mi][ni][rr] + b2[ni], 0.f);
        p += x * coef[ni];
      }
      #pragma unroll
      for (int m = 1; m <= 8; m <<= 1) p += __shfl_xor(p, m);
      if ((l & 15) == 0)
        part[wc][mi * 16 + (l >> 4) * 4 + rr] = p;
    }
  }
  __syncthreads();
  if (tid < 128) {
    int row = tid >> 1, hf = tid & 1;
    long grow = br * 64 + row;
    float v = hf ? (part[2][row] + part[3][row] + db3[0])
                 : (part[0][row] + part[1][row] + wb3[0]);
    ld[(size_t)hf * 32768 + grow] = v;
  }
}

// ---------------------------------------------------------------------------
// Finalize: masked softmax over K=32, prior, mu/sigma. (unchanged)
// ---------------------------------------------------------------------------
__global__ void finalize2_k(const float* __restrict__ uq, const float* __restrict__ ld,
                            const float* __restrict__ be2, const float* __restrict__ beb2,
                            const int* __restrict__ mask, const float* __restrict__ aff,
                            const float* __restrict__ lsg, float* __restrict__ out) {
  int n = blockIdx.x, t = threadIdx.x;
  __shared__ float s_red[4];
  float x = uq[(size_t)n * 768 + 512 + t];
  float pp = fmaxf(x, 0.f) * be2[t];
  #pragma unroll
  for (int m = 32; m >= 1; m >>= 1) pp += __shfl_xor(pp, m);
  if ((t & 63) == 0) s_red[t >> 6] = pp;
  __syncthreads();
  if (t < 64) {
    int kk = t & 31;
    int m = mask[n * 32 + kk];
    float lg = m ? ld[n * 32 + kk] : -1e9f;
    float dl = ld[32768 + n * 32 + kk];
    float mx = lg;
    #pragma unroll
    for (int mm = 16; mm >= 1; mm >>= 1) mx = fmaxf(mx, __shfl_xor(mx, mm));
    float e = expf(lg - mx);
    float s = e;
    #pragma unroll
    for (int mm = 16; mm >= 1; mm >>= 1) s += __shfl_xor(s, mm);
    float wgt = (e / s) * (m ? 1.f : 0.f);
    float nrm = wgt;
    #pragma unroll
    for (int mm = 16; mm >= 1; mm >>= 1) nrm += __shfl_xor(nrm, mm);
    wgt = (nrm > 0.f) ? wgt / fmaxf(nrm, 1e-8f) : 0.f;
    float tr = wgt * aff[n * 32 + kk];
    float co = wgt * dl;
    int am = m;
    #pragma unroll
    for (int mm = 16; mm >= 1; mm >>= 1) {
      tr += __shfl_xor(tr, mm);
      co += __shfl_xor(co, mm);
      am |= __shfl_xor(am, mm);
    }
    if (t == 0) {
      float prior = s_red[0] + s_red[1] + s_red[2] + s_red[3] + beb2[0] + 6.5f;
      float l0 = lsg[0];
      float sp = (l0 > 20.f) ? l0 : log1pf(expf(l0));
      float mu = am ? (tr + co) : prior;
      float sg = sp + (am ? 0.f : 0.15f) + 1e-4f;
      out[n] = mu;
      out[1024 + n] = sg;
    }
  }
}

// ---------------------------------------------------------------------------
extern "C" void kernel_launch(void* const* d_in, const int* in_sizes, int n_in,
                              void* d_out, int out_size, void* d_ws, size_t ws_size,
                              hipStream_t stream) {
  const float* np_ = (const float*)d_in[0];
  const float* nd_ = (const float*)d_in[1];
  const float* aff = (const float*)d_in[2];
  const float* ppr = (const float*)d_in[3];
  const float* trs = (const float*)d_in[4];
  const int*   msk = (const int*)d_in[5];
  const float* qp  = (const float*)d_in[6];
  const float* qd  = (const float*)d_in[7];
  const float* w1  = (const float*)d_in[8];
  const float* wb1 = (const float*)d_in[9];
  const float* w2  = (const float*)d_in[10];
  const float* wb2 = (const float*)d_in[11];
  const float* w3  = (const float*)d_in[12];
  const float* wb3 = (const float*)d_in[13];
  const float* d1  = (const float*)d_in[14];
  const float* db1 = (const float*)d_in[15];
  const float* d2  = (const float*)d_in[16];
  const float* db2 = (const float*)d_in[17];
  const float* d3  = (const float*)d_in[18];
  const float* db3 = (const float*)d_in[19];
  const float* be1 = (const float*)d_in[20];
  const float* beb1 = (const float*)d_in[21];
  const float* be2 = (const float*)d_in[22];
  const float* beb2 = (const float*)d_in[23];
  const float* lsg = (const float*)d_in[24];
  float* out = (float*)d_out;

  char* ws = (char*)d_ws;
  size_t off = 0;
  auto carve = [&](size_t bytes) -> void* {
    void* p = ws + off;
    off += (bytes + 511) & ~(size_t)511;
    return p;
  };
  float*          uq  = (float*)carve(1024ull * 768 * 4);
  unsigned short* h1  = (unsigned short*)carve(32768ull * 512 * 2);
  float*          ld  = (float*)carve(2ull * 32768 * 4);
  unsigned short* Bt1 = (unsigned short*)carve(512ull * 1536 * 2);
  unsigned short* Btq = (unsigned short*)carve(768ull * 1536 * 2);
  unsigned short* Bt2 = (unsigned short*)carve(256ull * 512 * 2);
  unsigned short* Aq  = (unsigned short*)carve(1024ull * 1536 * 2);
  float*          qn  = (float*)carve(1024ull * 4);
  (void)ws_size; (void)in_sizes; (void)n_in; (void)out_size;

  prepw_k<<<2048, 256, 0, stream>>>(w1, d1, be1, w2, d2, Bt1, Btq, Bt2);
  qprep_k<<<1024, 256, 0, stream>>>(qp, qd, Aq, qn);

  gemm0_k<<<dim3(8, 6), 256, 0, stream>>>(Aq, Btq, wb1, db1, beb1, uq);

  gemm1_k<<<256, 512, 0, stream>>>(np_, nd_, Bt1, uq, aff, ppr, trs,
                                   qd, qn, w1, d1, h1);

  gemm2_k<<<512, 256, 0, stream>>>(h1, Bt2, wb2, db2, w3, wb3, d3, db3, ld);

  finalize2_k<<<1024, 256, 0, stream>>>(uq, ld, be2, beb2, msk, aff, lsg, out);
}